// Round 1
// 612.105 us; speedup vs baseline: 1.0436x; 1.0436x over previous
//
#include <hip/hip_runtime.h>
#include <cstdint>

typedef unsigned short u16;
typedef unsigned int u32;
typedef float floatx4 __attribute__((ext_vector_type(4)));
typedef __bf16 bf16x8 __attribute__((ext_vector_type(8)));
typedef u16 u16x4 __attribute__((ext_vector_type(4)));

__device__ __forceinline__ u16 f2b(float f) {
  u32 u = __builtin_bit_cast(u32, f);
  u32 r = (u + 0x7fffu + ((u >> 16) & 1u)) >> 16;
  return (u16)r;
}
__device__ __forceinline__ float b2f(u16 b) {
  return __builtin_bit_cast(float, (u32)b << 16);
}
__device__ __forceinline__ float sigf(float x) { return 1.f / (1.f + __expf(-x)); }
__device__ __forceinline__ float tanhfast(float x) { return 2.f / (1.f + __expf(-2.f * x)) - 1.f; }

#define GLDS(gp, lp) __builtin_amdgcn_global_load_lds( \
    (const __attribute__((address_space(1))) u32*)(gp), \
    (__attribute__((address_space(3))) u32*)(lp), 16, 0, 0)

// ============================================================================
// 256x256-tile GEMM, BK=32, 4-deep circular LDS pipeline with counted vmcnt.
// C = A @ W^T (A:[M,K] bf16 K-contig, W:[N,K] bf16 K-contig), C bf16,
// per-column sum/sumsq atomically accumulated (BN stats).
// Requires: M%256==0, N%256==0, K%32==0, grid == (8,64) (XCD remap baked in).
// ============================================================================
template <int KT>
__global__ __launch_bounds__(512, 2) void gemm256(
    const u16* __restrict__ A, const u16* __restrict__ W, u16* __restrict__ C,
    int N, float* __restrict__ ssum, float* __restrict__ ssq) {
  constexpr int NT = KT / 32;  // K-tiles
  __shared__ __align__(16) u16 lds[4 * 16384];  // 4 slots x (A 16KB | B 16KB)

  const int tid = threadIdx.x;
  const int lane = tid & 63;
  const int wid = tid >> 6;
  const int wm = (wid >> 2) << 7;  // 0 / 128
  const int wn = (wid & 3) << 6;   // 0/64/128/192
  const int fr = lane & 15;
  const int fq = lane >> 4;

  // XCD-chunked bijective remap: grid is (8,64), dispatch linear = bx + by*8.
  // Each XCD gets 8 row-blocks x all col-blocks -> A-chunk (2MB) + W (2MB) in L2.
  const int l = blockIdx.x + (blockIdx.y << 3);
  const int xcd = l & 7;
  const int idx = l >> 3;
  const int bx = idx & 7;
  const int by = (xcd << 3) + (idx >> 3);
  const int m0 = by << 8;
  const int n0 = bx << 8;

  const u16* Ab = A + (size_t)m0 * KT;
  const u16* Wb = W + (size_t)n0 * KT;

  // Staging: 16B chunks. Per matrix per K-tile: 1024 chunks (256 rows x 4).
  // chunk q -> row r=q>>2, col c=q&3; swizzle: src col c' = c ^ ((r>>1)&3).
  // LDS dest linear (wave-uniform base + lane*16 satisfied since q = tid + l*512).
  const int q0 = tid, q1 = tid + 512;
  const int r0 = q0 >> 2, r1 = q1 >> 2;
  const int c0 = (q0 & 3) ^ ((r0 >> 1) & 3);
  const int c1 = (q1 & 3) ^ ((r1 >> 1) & 3);
  const u16* pa0 = Ab + (size_t)r0 * KT + c0 * 8;
  const u16* pa1 = Ab + (size_t)r1 * KT + c1 * 8;
  const u16* pb0 = Wb + (size_t)r0 * KT + c0 * 8;
  const u16* pb1 = Wb + (size_t)r1 * KT + c1 * 8;
  const int d0 = q0 * 8;  // u16 index of dest chunk
  const int d1 = q1 * 8;

#define STAGE(kt) do {                                      \
    const int _sl = ((kt) & 3) * 16384;                     \
    const int _ko = (kt) * 32;                              \
    GLDS(pa0 + _ko, &lds[_sl + d0]);                        \
    GLDS(pa1 + _ko, &lds[_sl + d1]);                        \
    GLDS(pb0 + _ko, &lds[_sl + 8192 + d0]);                 \
    GLDS(pb1 + _ko, &lds[_sl + 8192 + d1]);                 \
  } while (0)

  // ds_read offsets (u16 index within slot), swizzle matches staging.
  int aoffs[8], boffs[4];
#pragma unroll
  for (int mf = 0; mf < 8; ++mf) {
    const int R = wm + mf * 16 + fr;
    aoffs[mf] = R * 32 + ((fq ^ ((R >> 1) & 3)) << 3);
  }
#pragma unroll
  for (int nf = 0; nf < 4; ++nf) {
    const int R = wn + nf * 16 + fr;
    boffs[nf] = 8192 + R * 32 + ((fq ^ ((R >> 1) & 3)) << 3);
  }

  floatx4 acc[8][4] = {};

  STAGE(0);
  STAGE(1);
  STAGE(2);

#pragma unroll
  for (int t = 0; t < NT; ++t) {
    // Counted wait: keep tiles t+1,t+2 in flight; drain only tile t.
    if (NT - 1 - t >= 2)      asm volatile("s_waitcnt vmcnt(8)" ::: "memory");
    else if (NT - 1 - t == 1) asm volatile("s_waitcnt vmcnt(4)" ::: "memory");
    else                      asm volatile("s_waitcnt vmcnt(0)" ::: "memory");
    __builtin_amdgcn_s_barrier();
    __builtin_amdgcn_sched_barrier(0);  // nothing crosses the barrier

    if (t + 3 < NT) STAGE(t + 3);  // writes slot (t-1)&3: freed by last iter's
                                   // lgkmcnt(0) + this barrier

    const int sl = (t & 3) * 16384;
    bf16x8 bfv[4];
#pragma unroll
    for (int nf = 0; nf < 4; ++nf) bfv[nf] = *(const bf16x8*)&lds[sl + boffs[nf]];
#pragma unroll
    for (int mf = 0; mf < 8; ++mf) {
      const bf16x8 af = *(const bf16x8*)&lds[sl + aoffs[mf]];
#pragma unroll
      for (int nf = 0; nf < 4; ++nf)
        acc[mf][nf] = __builtin_amdgcn_mfma_f32_16x16x32_bf16(af, bfv[nf], acc[mf][nf], 0, 0, 0);
    }
    asm volatile("s_waitcnt lgkmcnt(0)" ::: "memory");  // slot-reuse proof
    __builtin_amdgcn_sched_barrier(0);
  }
#undef STAGE

  // Epilogue: C write (bf16) + per-column stats.
#pragma unroll
  for (int mf = 0; mf < 8; ++mf)
#pragma unroll
    for (int nf = 0; nf < 4; ++nf) {
      const int col = n0 + wn + nf * 16 + fr;
#pragma unroll
      for (int r = 0; r < 4; ++r) {
        const int row = m0 + wm + mf * 16 + fq * 4 + r;
        C[(size_t)row * N + col] = f2b(acc[mf][nf][r]);
      }
    }
#pragma unroll
  for (int nf = 0; nf < 4; ++nf) {
    float s = 0.f, qv = 0.f;
#pragma unroll
    for (int mf = 0; mf < 8; ++mf)
#pragma unroll
      for (int r = 0; r < 4; ++r) {
        const float v = acc[mf][nf][r];
        s += v;
        qv += v * v;
      }
    s += __shfl_xor(s, 16);
    s += __shfl_xor(s, 32);
    qv += __shfl_xor(qv, 16);
    qv += __shfl_xor(qv, 32);
    if (fq == 0) {
      atomicAdd(&ssum[n0 + wn + nf * 16 + fr], s);
      atomicAdd(&ssq[n0 + wn + nf * 16 + fr], qv);
    }
  }
}

// ============================================================================
// Old 128x128 kernel: kept for the output projection (N=256, BIAS path).
// ============================================================================
template <int STATS, int BIAS>
__global__ __launch_bounds__(256) void gemm_bt(
    const u16* __restrict__ A, const u16* __restrict__ W, void* __restrict__ Cv,
    int N, int K, float* __restrict__ ssum, float* __restrict__ ssq,
    const float* __restrict__ bias) {
  __shared__ u16 As[128 * 32];
  __shared__ u16 Bs[128 * 32];
  const int tid = threadIdx.x;
  const int lane = tid & 63;
  const int wave = tid >> 6;
  const int wm = (wave >> 1) << 6;
  const int wn = (wave & 1) << 6;
  const int m0 = blockIdx.y * 128;
  const int n0 = blockIdx.x * 128;
  const u16* Ab = A + (size_t)m0 * K;
  const u16* Wb = W + (size_t)n0 * K;
  const size_t soff = (size_t)(tid >> 2) * K + ((tid & 3) << 3);
  const size_t soff2 = soff + (size_t)64 * K;
  const int fr = lane & 15;
  const int fq = lane >> 4;
  const int aoff = fr * 32 + fq * 8;

  floatx4 acc[4][4] = {};

  for (int k0 = 0; k0 < K; k0 += 32) {
    __syncthreads();
    GLDS(Ab + soff + k0, &As[tid * 8]);
    GLDS(Ab + soff2 + k0, &As[tid * 8 + 2048]);
    GLDS(Wb + soff + k0, &Bs[tid * 8]);
    GLDS(Wb + soff2 + k0, &Bs[tid * 8 + 2048]);
    __syncthreads();
    bf16x8 af[4], bfv[4];
#pragma unroll
    for (int i = 0; i < 4; ++i) af[i] = *(const bf16x8*)&As[(wm + i * 16) * 32 + aoff];
#pragma unroll
    for (int j = 0; j < 4; ++j) bfv[j] = *(const bf16x8*)&Bs[(wn + j * 16) * 32 + aoff];
#pragma unroll
    for (int i = 0; i < 4; ++i)
#pragma unroll
      for (int j = 0; j < 4; ++j)
        acc[i][j] = __builtin_amdgcn_mfma_f32_16x16x32_bf16(af[i], bfv[j], acc[i][j], 0, 0, 0);
  }

  if (BIAS) {
    float* Cf = (float*)Cv;
#pragma unroll
    for (int i = 0; i < 4; ++i)
#pragma unroll
      for (int j = 0; j < 4; ++j) {
        const int col = n0 + wn + j * 16 + fr;
        const float bv = bias[col];
#pragma unroll
        for (int r = 0; r < 4; ++r) {
          const int row = m0 + wm + i * 16 + fq * 4 + r;
          Cf[(size_t)row * N + col] = acc[i][j][r] + bv;
        }
      }
  } else {
    u16* Cb = (u16*)Cv;
#pragma unroll
    for (int i = 0; i < 4; ++i)
#pragma unroll
      for (int j = 0; j < 4; ++j) {
        const int col = n0 + wn + j * 16 + fr;
#pragma unroll
        for (int r = 0; r < 4; ++r) {
          const int row = m0 + wm + i * 16 + fq * 4 + r;
          Cb[(size_t)row * N + col] = f2b(acc[i][j][r]);
        }
      }
  }

  if (STATS) {
#pragma unroll
    for (int j = 0; j < 4; ++j) {
      float s = 0.f, q = 0.f;
#pragma unroll
      for (int i = 0; i < 4; ++i)
#pragma unroll
        for (int r = 0; r < 4; ++r) {
          const float v = acc[i][j][r];
          s += v;
          q += v * v;
        }
      s += __shfl_xor(s, 16);
      s += __shfl_xor(s, 32);
      q += __shfl_xor(q, 16);
      q += __shfl_xor(q, 32);
      if (fq == 0) {
        atomicAdd(&ssum[n0 + wn + j * 16 + fr], s);
        atomicAdd(&ssq[n0 + wn + j * 16 + fr], q);
      }
    }
  }
}

// concat [x | y | zeros] -> bf16 [B, 288]
__global__ void pad_inp_k(const float* __restrict__ x, const float* __restrict__ y,
                          u16* __restrict__ o) {
  const int idx = blockIdx.x * 256 + threadIdx.x;  // B*288
  const int b = idx / 288;
  const int c = idx - b * 288;
  float v = 0.f;
  if (c < 256) v = x[b * 256 + c];
  else if (c == 256) v = y[b];
  o[idx] = f2b(v);
}

// Wx0 [2048,257] -> bf16 [2048,288] zero-padded
__global__ void pad_w_k(const float* __restrict__ w, u16* __restrict__ o) {
  const int idx = blockIdx.x * 256 + threadIdx.x;  // 2048*288
  const int r = idx / 288;
  const int c = idx - r * 288;
  o[idx] = f2b(c < 257 ? w[r * 257 + c] : 0.f);
}

__global__ void f2b_k(const float4* __restrict__ in, u16x4* __restrict__ o, int n4) {
  const int idx = blockIdx.x * 256 + threadIdx.x;
  if (idx < n4) {
    const float4 v = in[idx];
    u16x4 r;
    r.x = f2b(v.x);
    r.y = f2b(v.y);
    r.z = f2b(v.z);
    r.w = f2b(v.w);
    o[idx] = r;
  }
}

// stats layout per layer: [sum_x, sq_x, sum_h, sq_h] each 2048
// coef layout per layer:  [ax, ah, cb] each 2048
__global__ void coef_k(const float* __restrict__ st, const float* __restrict__ gx,
                       const float* __restrict__ bx, const float* __restrict__ gh,
                       const float* __restrict__ bh, float* __restrict__ cf, float invB) {
  const int j = blockIdx.x * 256 + threadIdx.x;  // 2048
  const float mx = st[j] * invB;
  const float vx = st[2048 + j] * invB - mx * mx;
  const float ax = gx[j] * rsqrtf(vx + 1e-5f);
  const float mh = st[4096 + j] * invB;
  const float vh = st[6144 + j] * invB - mh * mh;
  const float ah = gh[j] * rsqrtf(vh + 1e-5f);
  cf[j] = ax;
  cf[2048 + j] = ah;
  cf[4096 + j] = bx[j] - mx * ax + bh[j] - mh * ah;
}

// fused BN-affine + LSTM cell; 2 columns per thread
__global__ void cell_k(const u16* __restrict__ Zx, const u16* __restrict__ Zh,
                       const float* __restrict__ coef, const float* __restrict__ cin,
                       float* __restrict__ hout, float* __restrict__ cout,
                       u16* __restrict__ hb) {
  const int idx = blockIdx.x * 256 + threadIdx.x;  // B*256
  const int b = idx >> 8;
  const int j2 = (idx & 255) << 1;
  const size_t rb = (size_t)b << 11;
  float gv[4][2];
#pragma unroll
  for (int g = 0; g < 4; ++g) {
    const int col = (g << 9) + j2;
    const u32 zx = *(const u32*)(Zx + rb + col);
    const u32 zh = *(const u32*)(Zh + rb + col);
#pragma unroll
    for (int t = 0; t < 2; ++t) {
      const float zxv = b2f((u16)(zx >> (16 * t)));
      const float zhv = b2f((u16)(zh >> (16 * t)));
      gv[g][t] = coef[col + t] * zxv + coef[2048 + col + t] * zhv + coef[4096 + col + t];
    }
  }
  const size_t ob = ((size_t)b << 9) + j2;
  const float2 cp = *(const float2*)(cin + ob);
  float cn[2], hn[2];
#pragma unroll
  for (int t = 0; t < 2; ++t) {
    const float cprev = t ? cp.y : cp.x;
    const float cc = sigf(gv[0][t]) * cprev + sigf(gv[1][t]) * tanhfast(gv[3][t]);
    cn[t] = cc;
    hn[t] = sigf(gv[2][t]) * tanhfast(cc);
  }
  *(float2*)(cout + ob) = make_float2(cn[0], cn[1]);
  *(float2*)(hout + ob) = make_float2(hn[0], hn[1]);
  *(u32*)(hb + ob) = (u32)f2b(hn[0]) | ((u32)f2b(hn[1]) << 16);
}

extern "C" void kernel_launch(void* const* d_in, const int* in_sizes, int n_in,
                              void* d_out, int out_size, void* d_ws, size_t ws_size,
                              hipStream_t stream) {
  (void)in_sizes; (void)n_in; (void)out_size; (void)ws_size;
  constexpr int B = 16384, H = 512, G = 2048, KP = 288, K1 = 512, NOUT = 256;

  const float* x = (const float*)d_in[0];
  const float* y = (const float*)d_in[1];
  const float* h0 = (const float*)d_in[2];
  const float* c0 = (const float*)d_in[3];
  const float* Wx0 = (const float*)d_in[4];
  const float* Wh0 = (const float*)d_in[5];
  const float* gx0 = (const float*)d_in[6];
  const float* bx0 = (const float*)d_in[7];
  const float* gh0 = (const float*)d_in[8];
  const float* bh0 = (const float*)d_in[9];
  const float* Wx1 = (const float*)d_in[10];
  const float* Wh1 = (const float*)d_in[11];
  const float* gx1 = (const float*)d_in[12];
  const float* bx1 = (const float*)d_in[13];
  const float* gh1 = (const float*)d_in[14];
  const float* bh1 = (const float*)d_in[15];
  const float* Wo = (const float*)d_in[16];
  const float* bo = (const float*)d_in[17];

  char* p = (char*)d_ws;
  u16* Zx = (u16*)p;   p += (size_t)B * G * 2;
  u16* Zh = (u16*)p;   p += (size_t)B * G * 2;
  u16* h0b = (u16*)p;  p += (size_t)2 * B * H * 2;
  u16* h1b = (u16*)p;  p += (size_t)B * H * 2;   // reused for h2 bf16
  u16* inpb = (u16*)p; p += (size_t)B * KP * 2;
  u16* wx0b = (u16*)p; p += (size_t)G * KP * 2;
  u16* wh0b = (u16*)p; p += (size_t)G * K1 * 2;
  u16* wx1b = (u16*)p; p += (size_t)G * K1 * 2;
  u16* wh1b = (u16*)p; p += (size_t)G * K1 * 2;
  u16* wob = (u16*)p;  p += (size_t)NOUT * K1 * 2;
  float* stats = (float*)p; p += (size_t)8 * G * 4;
  float* coef = (float*)p;  p += (size_t)6 * G * 4;

  float* out_o = (float*)d_out;                     // [B,256]
  float* h_o = out_o + (size_t)B * NOUT;            // [2,B,512]
  float* c_o = h_o + (size_t)2 * B * H;             // [2,B,512]

  hipMemsetAsync(stats, 0, (size_t)8 * G * sizeof(float), stream);

  pad_inp_k<<<B * KP / 256, 256, 0, stream>>>(x, y, inpb);
  pad_w_k<<<G * KP / 256, 256, 0, stream>>>(Wx0, wx0b);
  f2b_k<<<2 * B * H / 4 / 256, 256, 0, stream>>>((const float4*)h0, (u16x4*)h0b, 2 * B * H / 4);
  f2b_k<<<G * K1 / 4 / 256, 256, 0, stream>>>((const float4*)Wh0, (u16x4*)wh0b, G * K1 / 4);
  f2b_k<<<G * K1 / 4 / 256, 256, 0, stream>>>((const float4*)Wx1, (u16x4*)wx1b, G * K1 / 4);
  f2b_k<<<G * K1 / 4 / 256, 256, 0, stream>>>((const float4*)Wh1, (u16x4*)wh1b, G * K1 / 4);
  f2b_k<<<NOUT * K1 / 4 / 256, 256, 0, stream>>>((const float4*)Wo, (u16x4*)wob, NOUT * K1 / 4);

  const dim3 blk512(512);
  const dim3 g256(G / 256, B / 256);  // (8, 64)

  // layer 0
  gemm256<KP><<<g256, blk512, 0, stream>>>(inpb, wx0b, Zx, G, stats + 0 * G, stats + 1 * G);
  gemm256<K1><<<g256, blk512, 0, stream>>>(h0b, wh0b, Zh, G, stats + 2 * G, stats + 3 * G);
  coef_k<<<G / 256, 256, 0, stream>>>(stats, gx0, bx0, gh0, bh0, coef, 1.f / B);
  cell_k<<<B, 256, 0, stream>>>(Zx, Zh, coef, c0, h_o, c_o, h1b);

  // layer 1
  gemm256<K1><<<g256, blk512, 0, stream>>>(h1b, wx1b, Zx, G, stats + 4 * G, stats + 5 * G);
  gemm256<K1><<<g256, blk512, 0, stream>>>(h0b + (size_t)B * H, wh1b, Zh, G, stats + 6 * G, stats + 7 * G);
  coef_k<<<G / 256, 256, 0, stream>>>(stats + 4 * G, gx1, bx1, gh1, bh1, coef + 3 * G, 1.f / B);
  cell_k<<<B, 256, 0, stream>>>(Zx, Zh, coef + 3 * G, c0 + (size_t)B * H,
                                h_o + (size_t)B * H, c_o + (size_t)B * H, h1b);

  // output projection (old 128x128 kernel: N=256 grid = (2,128))
  const dim3 blk(256);
  const dim3 gout(NOUT / 128, B / 128);
  gemm_bt<0, 1><<<gout, blk, 0, stream>>>(h1b, wob, out_o, NOUT, K1, nullptr, nullptr, bo);
}

// Round 2
// 600.810 us; speedup vs baseline: 1.0633x; 1.0188x over previous
//
#include <hip/hip_runtime.h>
#include <cstdint>

typedef unsigned short u16;
typedef unsigned int u32;
typedef float floatx4 __attribute__((ext_vector_type(4)));
typedef __bf16 bf16x8 __attribute__((ext_vector_type(8)));
typedef u16 u16x4 __attribute__((ext_vector_type(4)));

__device__ __forceinline__ u16 f2b(float f) {
  u32 u = __builtin_bit_cast(u32, f);
  u32 r = (u + 0x7fffu + ((u >> 16) & 1u)) >> 16;
  return (u16)r;
}
__device__ __forceinline__ float b2f(u16 b) {
  return __builtin_bit_cast(float, (u32)b << 16);
}
__device__ __forceinline__ float sigf(float x) { return 1.f / (1.f + __expf(-x)); }
__device__ __forceinline__ float tanhfast(float x) { return 2.f / (1.f + __expf(-2.f * x)) - 1.f; }

#define GLDS(gp, lp) __builtin_amdgcn_global_load_lds( \
    (const __attribute__((address_space(1))) u32*)(gp), \
    (__attribute__((address_space(3))) u32*)(lp), 16, 0, 0)

// ============================================================================
// 128x128-tile GEMM, BK=32, 3-slot circular LDS pipeline, counted vmcnt.
// 256 threads / 4 waves, wave tile 64x64 (acc[4][4]) -> ~3 blocks/CU.
// C = A @ W^T (A:[M,K] bf16 K-contig, W:[N,K] bf16 K-contig), C bf16,
// per-column sum/sumsq atomically accumulated (BN stats).
// Requires: M%128==0, N%128==0, K%32==0, grid == (16, M/128) (XCD remap).
// ============================================================================
template <int KT>
__global__ __launch_bounds__(256) void gemm_p(
    const u16* __restrict__ A, const u16* __restrict__ W, u16* __restrict__ C,
    int N, float* __restrict__ ssum, float* __restrict__ ssq) {
  constexpr int NT = KT / 32;
  __shared__ __align__(16) u16 lds[3 * 8192];  // 3 slots x (A 8KB | B 8KB)

  const int tid = threadIdx.x;
  const int lane = tid & 63;
  const int wid = tid >> 6;
  const int wm = (wid >> 1) << 6;  // 0 / 64
  const int wn = (wid & 1) << 6;   // 0 / 64
  const int fr = lane & 15;
  const int fq = lane >> 4;

  // XCD-chunked bijective remap: grid (16,128) = 2048 blocks, 256/XCD.
  // XCD x owns by in [x*16, x*16+16) x all bx -> A-chunk 2MB + W 2MB in its L2.
  const int l = blockIdx.x + (blockIdx.y << 4);
  const int xcd = l & 7;
  const int idx = l >> 3;          // 0..255
  const int bx = idx & 15;
  const int by = (xcd << 4) + (idx >> 4);
  const int m0 = by << 7;
  const int n0 = bx << 7;

  const u16* Ab = A + (size_t)m0 * KT;
  const u16* Wb = W + (size_t)n0 * KT;

  // Staging: 16B chunks, 512 per matrix per K-tile (128 rows x 4 chunks).
  // chunk q -> row r=q>>2, col c=q&3; swizzle src col c' = c ^ ((r>>1)&3).
  // Thread handles q=tid and q=tid+256 per matrix (row +64: same swizzle).
  const int ra = tid >> 2;
  const int ca = (tid & 3) ^ ((ra >> 1) & 3);
  const u16* pa0 = Ab + (size_t)ra * KT + ca * 8;
  const u16* pa1 = pa0 + (size_t)64 * KT;
  const u16* pb0 = Wb + (size_t)ra * KT + ca * 8;
  const u16* pb1 = pb0 + (size_t)64 * KT;
  const int da = tid * 8;          // A dest (u16 idx), second chunk +2048
  const int db = 4096 + tid * 8;   // B dest

#define STAGE(kt) do {                                   \
    const int _sl = ((kt) % 3) * 8192;                   \
    const int _ko = (kt) * 32;                           \
    GLDS(pa0 + _ko, &lds[_sl + da]);                     \
    GLDS(pa1 + _ko, &lds[_sl + da + 2048]);              \
    GLDS(pb0 + _ko, &lds[_sl + db]);                     \
    GLDS(pb1 + _ko, &lds[_sl + db + 2048]);              \
  } while (0)

  // ds_read offsets (u16 idx within slot); swizzle matches staging.
  int aoffs[4], boffs[4];
#pragma unroll
  for (int mf = 0; mf < 4; ++mf) {
    const int R = wm + mf * 16 + fr;
    aoffs[mf] = R * 32 + ((fq ^ ((R >> 1) & 3)) << 3);
  }
#pragma unroll
  for (int nf = 0; nf < 4; ++nf) {
    const int R = wn + nf * 16 + fr;
    boffs[nf] = 4096 + R * 32 + ((fq ^ ((R >> 1) & 3)) << 3);
  }

  floatx4 acc[4][4] = {};

  STAGE(0);
  STAGE(1);

#pragma unroll
  for (int t = 0; t < NT; ++t) {
    // Drain tile t's 4 loads; keep tile t+1's 4 in flight (in-order return).
    if (t == NT - 1) asm volatile("s_waitcnt vmcnt(0)" ::: "memory");
    else             asm volatile("s_waitcnt vmcnt(4)" ::: "memory");
    __builtin_amdgcn_s_barrier();
    __builtin_amdgcn_sched_barrier(0);

    if (t + 2 < NT) STAGE(t + 2);  // slot (t+2)%3 == (t-1)%3: freed by last
                                   // iter's lgkmcnt(0) + this barrier

    const int sl = (t % 3) * 8192;
    bf16x8 bfv[4];
#pragma unroll
    for (int nf = 0; nf < 4; ++nf) bfv[nf] = *(const bf16x8*)&lds[sl + boffs[nf]];
    __builtin_amdgcn_s_setprio(1);
#pragma unroll
    for (int mf = 0; mf < 4; ++mf) {
      const bf16x8 af = *(const bf16x8*)&lds[sl + aoffs[mf]];
#pragma unroll
      for (int nf = 0; nf < 4; ++nf)
        acc[mf][nf] = __builtin_amdgcn_mfma_f32_16x16x32_bf16(af, bfv[nf], acc[mf][nf], 0, 0, 0);
    }
    __builtin_amdgcn_s_setprio(0);
    asm volatile("s_waitcnt lgkmcnt(0)" ::: "memory");  // reads retired before next barrier
    __builtin_amdgcn_sched_barrier(0);
  }
#undef STAGE

  // Epilogue: C write (bf16) + per-column stats.
#pragma unroll
  for (int mf = 0; mf < 4; ++mf)
#pragma unroll
    for (int nf = 0; nf < 4; ++nf) {
      const int col = n0 + wn + nf * 16 + fr;
#pragma unroll
      for (int r = 0; r < 4; ++r) {
        const int row = m0 + wm + mf * 16 + fq * 4 + r;
        C[(size_t)row * N + col] = f2b(acc[mf][nf][r]);
      }
    }
#pragma unroll
  for (int nf = 0; nf < 4; ++nf) {
    float s = 0.f, qv = 0.f;
#pragma unroll
    for (int mf = 0; mf < 4; ++mf)
#pragma unroll
      for (int r = 0; r < 4; ++r) {
        const float v = acc[mf][nf][r];
        s += v;
        qv += v * v;
      }
    s += __shfl_xor(s, 16);
    s += __shfl_xor(s, 32);
    qv += __shfl_xor(qv, 16);
    qv += __shfl_xor(qv, 32);
    if (fq == 0) {
      atomicAdd(&ssum[n0 + wn + nf * 16 + fr], s);
      atomicAdd(&ssq[n0 + wn + nf * 16 + fr], qv);
    }
  }
}

// ============================================================================
// Old 128x128 2-barrier kernel: kept for the output projection (N=256, BIAS).
// ============================================================================
template <int STATS, int BIAS>
__global__ __launch_bounds__(256) void gemm_bt(
    const u16* __restrict__ A, const u16* __restrict__ W, void* __restrict__ Cv,
    int N, int K, float* __restrict__ ssum, float* __restrict__ ssq,
    const float* __restrict__ bias) {
  __shared__ u16 As[128 * 32];
  __shared__ u16 Bs[128 * 32];
  const int tid = threadIdx.x;
  const int lane = tid & 63;
  const int wave = tid >> 6;
  const int wm = (wave >> 1) << 6;
  const int wn = (wave & 1) << 6;
  const int m0 = blockIdx.y * 128;
  const int n0 = blockIdx.x * 128;
  const u16* Ab = A + (size_t)m0 * K;
  const u16* Wb = W + (size_t)n0 * K;
  const size_t soff = (size_t)(tid >> 2) * K + ((tid & 3) << 3);
  const size_t soff2 = soff + (size_t)64 * K;
  const int fr = lane & 15;
  const int fq = lane >> 4;
  const int aoff = fr * 32 + fq * 8;

  floatx4 acc[4][4] = {};

  for (int k0 = 0; k0 < K; k0 += 32) {
    __syncthreads();
    GLDS(Ab + soff + k0, &As[tid * 8]);
    GLDS(Ab + soff2 + k0, &As[tid * 8 + 2048]);
    GLDS(Wb + soff + k0, &Bs[tid * 8]);
    GLDS(Wb + soff2 + k0, &Bs[tid * 8 + 2048]);
    __syncthreads();
    bf16x8 af[4], bfv[4];
#pragma unroll
    for (int i = 0; i < 4; ++i) af[i] = *(const bf16x8*)&As[(wm + i * 16) * 32 + aoff];
#pragma unroll
    for (int j = 0; j < 4; ++j) bfv[j] = *(const bf16x8*)&Bs[(wn + j * 16) * 32 + aoff];
#pragma unroll
    for (int i = 0; i < 4; ++i)
#pragma unroll
      for (int j = 0; j < 4; ++j)
        acc[i][j] = __builtin_amdgcn_mfma_f32_16x16x32_bf16(af[i], bfv[j], acc[i][j], 0, 0, 0);
  }

  if (BIAS) {
    float* Cf = (float*)Cv;
#pragma unroll
    for (int i = 0; i < 4; ++i)
#pragma unroll
      for (int j = 0; j < 4; ++j) {
        const int col = n0 + wn + j * 16 + fr;
        const float bv = bias[col];
#pragma unroll
        for (int r = 0; r < 4; ++r) {
          const int row = m0 + wm + i * 16 + fq * 4 + r;
          Cf[(size_t)row * N + col] = acc[i][j][r] + bv;
        }
      }
  } else {
    u16* Cb = (u16*)Cv;
#pragma unroll
    for (int i = 0; i < 4; ++i)
#pragma unroll
      for (int j = 0; j < 4; ++j) {
        const int col = n0 + wn + j * 16 + fr;
#pragma unroll
        for (int r = 0; r < 4; ++r) {
          const int row = m0 + wm + i * 16 + fq * 4 + r;
          Cb[(size_t)row * N + col] = f2b(acc[i][j][r]);
        }
      }
  }

  if (STATS) {
#pragma unroll
    for (int j = 0; j < 4; ++j) {
      float s = 0.f, q = 0.f;
#pragma unroll
      for (int i = 0; i < 4; ++i)
#pragma unroll
        for (int r = 0; r < 4; ++r) {
          const float v = acc[i][j][r];
          s += v;
          q += v * v;
        }
      s += __shfl_xor(s, 16);
      s += __shfl_xor(s, 32);
      q += __shfl_xor(q, 16);
      q += __shfl_xor(q, 32);
      if (fq == 0) {
        atomicAdd(&ssum[n0 + wn + j * 16 + fr], s);
        atomicAdd(&ssq[n0 + wn + j * 16 + fr], q);
      }
    }
  }
}

// concat [x | y | zeros] -> bf16 [B, 288]
__global__ void pad_inp_k(const float* __restrict__ x, const float* __restrict__ y,
                          u16* __restrict__ o) {
  const int idx = blockIdx.x * 256 + threadIdx.x;  // B*288
  const int b = idx / 288;
  const int c = idx - b * 288;
  float v = 0.f;
  if (c < 256) v = x[b * 256 + c];
  else if (c == 256) v = y[b];
  o[idx] = f2b(v);
}

// Wx0 [2048,257] -> bf16 [2048,288] zero-padded
__global__ void pad_w_k(const float* __restrict__ w, u16* __restrict__ o) {
  const int idx = blockIdx.x * 256 + threadIdx.x;  // 2048*288
  const int r = idx / 288;
  const int c = idx - r * 288;
  o[idx] = f2b(c < 257 ? w[r * 257 + c] : 0.f);
}

__global__ void f2b_k(const float4* __restrict__ in, u16x4* __restrict__ o, int n4) {
  const int idx = blockIdx.x * 256 + threadIdx.x;
  if (idx < n4) {
    const float4 v = in[idx];
    u16x4 r;
    r.x = f2b(v.x);
    r.y = f2b(v.y);
    r.z = f2b(v.z);
    r.w = f2b(v.w);
    o[idx] = r;
  }
}

// stats layout per layer: [sum_x, sq_x, sum_h, sq_h] each 2048
// coef layout per layer:  [ax, ah, cb] each 2048
__global__ void coef_k(const float* __restrict__ st, const float* __restrict__ gx,
                       const float* __restrict__ bx, const float* __restrict__ gh,
                       const float* __restrict__ bh, float* __restrict__ cf, float invB) {
  const int j = blockIdx.x * 256 + threadIdx.x;  // 2048
  const float mx = st[j] * invB;
  const float vx = st[2048 + j] * invB - mx * mx;
  const float ax = gx[j] * rsqrtf(vx + 1e-5f);
  const float mh = st[4096 + j] * invB;
  const float vh = st[6144 + j] * invB - mh * mh;
  const float ah = gh[j] * rsqrtf(vh + 1e-5f);
  cf[j] = ax;
  cf[2048 + j] = ah;
  cf[4096 + j] = bx[j] - mx * ax + bh[j] - mh * ah;
}

// fused BN-affine + LSTM cell; 2 columns per thread
__global__ void cell_k(const u16* __restrict__ Zx, const u16* __restrict__ Zh,
                       const float* __restrict__ coef, const float* __restrict__ cin,
                       float* __restrict__ hout, float* __restrict__ cout,
                       u16* __restrict__ hb) {
  const int idx = blockIdx.x * 256 + threadIdx.x;  // B*256
  const int b = idx >> 8;
  const int j2 = (idx & 255) << 1;
  const size_t rb = (size_t)b << 11;
  float gv[4][2];
#pragma unroll
  for (int g = 0; g < 4; ++g) {
    const int col = (g << 9) + j2;
    const u32 zx = *(const u32*)(Zx + rb + col);
    const u32 zh = *(const u32*)(Zh + rb + col);
#pragma unroll
    for (int t = 0; t < 2; ++t) {
      const float zxv = b2f((u16)(zx >> (16 * t)));
      const float zhv = b2f((u16)(zh >> (16 * t)));
      gv[g][t] = coef[col + t] * zxv + coef[2048 + col + t] * zhv + coef[4096 + col + t];
    }
  }
  const size_t ob = ((size_t)b << 9) + j2;
  const float2 cp = *(const float2*)(cin + ob);
  float cn[2], hn[2];
#pragma unroll
  for (int t = 0; t < 2; ++t) {
    const float cprev = t ? cp.y : cp.x;
    const float cc = sigf(gv[0][t]) * cprev + sigf(gv[1][t]) * tanhfast(gv[3][t]);
    cn[t] = cc;
    hn[t] = sigf(gv[2][t]) * tanhfast(cc);
  }
  *(float2*)(cout + ob) = make_float2(cn[0], cn[1]);
  *(float2*)(hout + ob) = make_float2(hn[0], hn[1]);
  *(u32*)(hb + ob) = (u32)f2b(hn[0]) | ((u32)f2b(hn[1]) << 16);
}

extern "C" void kernel_launch(void* const* d_in, const int* in_sizes, int n_in,
                              void* d_out, int out_size, void* d_ws, size_t ws_size,
                              hipStream_t stream) {
  (void)in_sizes; (void)n_in; (void)out_size; (void)ws_size;
  constexpr int B = 16384, H = 512, G = 2048, KP = 288, K1 = 512, NOUT = 256;

  const float* x = (const float*)d_in[0];
  const float* y = (const float*)d_in[1];
  const float* h0 = (const float*)d_in[2];
  const float* c0 = (const float*)d_in[3];
  const float* Wx0 = (const float*)d_in[4];
  const float* Wh0 = (const float*)d_in[5];
  const float* gx0 = (const float*)d_in[6];
  const float* bx0 = (const float*)d_in[7];
  const float* gh0 = (const float*)d_in[8];
  const float* bh0 = (const float*)d_in[9];
  const float* Wx1 = (const float*)d_in[10];
  const float* Wh1 = (const float*)d_in[11];
  const float* gx1 = (const float*)d_in[12];
  const float* bx1 = (const float*)d_in[13];
  const float* gh1 = (const float*)d_in[14];
  const float* bh1 = (const float*)d_in[15];
  const float* Wo = (const float*)d_in[16];
  const float* bo = (const float*)d_in[17];

  char* p = (char*)d_ws;
  u16* Zx = (u16*)p;   p += (size_t)B * G * 2;
  u16* Zh = (u16*)p;   p += (size_t)B * G * 2;
  u16* h0b = (u16*)p;  p += (size_t)2 * B * H * 2;
  u16* h1b = (u16*)p;  p += (size_t)B * H * 2;   // reused for h2 bf16
  u16* inpb = (u16*)p; p += (size_t)B * KP * 2;
  u16* wx0b = (u16*)p; p += (size_t)G * KP * 2;
  u16* wh0b = (u16*)p; p += (size_t)G * K1 * 2;
  u16* wx1b = (u16*)p; p += (size_t)G * K1 * 2;
  u16* wh1b = (u16*)p; p += (size_t)G * K1 * 2;
  u16* wob = (u16*)p;  p += (size_t)NOUT * K1 * 2;
  float* stats = (float*)p; p += (size_t)8 * G * 4;
  float* coef = (float*)p;  p += (size_t)6 * G * 4;

  float* out_o = (float*)d_out;                     // [B,256]
  float* h_o = out_o + (size_t)B * NOUT;            // [2,B,512]
  float* c_o = h_o + (size_t)2 * B * H;             // [2,B,512]

  hipMemsetAsync(stats, 0, (size_t)8 * G * sizeof(float), stream);

  pad_inp_k<<<B * KP / 256, 256, 0, stream>>>(x, y, inpb);
  pad_w_k<<<G * KP / 256, 256, 0, stream>>>(Wx0, wx0b);
  f2b_k<<<2 * B * H / 4 / 256, 256, 0, stream>>>((const float4*)h0, (u16x4*)h0b, 2 * B * H / 4);
  f2b_k<<<G * K1 / 4 / 256, 256, 0, stream>>>((const float4*)Wh0, (u16x4*)wh0b, G * K1 / 4);
  f2b_k<<<G * K1 / 4 / 256, 256, 0, stream>>>((const float4*)Wx1, (u16x4*)wx1b, G * K1 / 4);
  f2b_k<<<G * K1 / 4 / 256, 256, 0, stream>>>((const float4*)Wh1, (u16x4*)wh1b, G * K1 / 4);
  f2b_k<<<NOUT * K1 / 4 / 256, 256, 0, stream>>>((const float4*)Wo, (u16x4*)wob, NOUT * K1 / 4);

  const dim3 blk(256);
  const dim3 gbig(G / 128, B / 128);  // (16, 128) = 2048 blocks

  // layer 0
  gemm_p<KP><<<gbig, blk, 0, stream>>>(inpb, wx0b, Zx, G, stats + 0 * G, stats + 1 * G);
  gemm_p<K1><<<gbig, blk, 0, stream>>>(h0b, wh0b, Zh, G, stats + 2 * G, stats + 3 * G);
  coef_k<<<G / 256, 256, 0, stream>>>(stats, gx0, bx0, gh0, bh0, coef, 1.f / B);
  cell_k<<<B, 256, 0, stream>>>(Zx, Zh, coef, c0, h_o, c_o, h1b);

  // layer 1
  gemm_p<K1><<<gbig, blk, 0, stream>>>(h1b, wx1b, Zx, G, stats + 4 * G, stats + 5 * G);
  gemm_p<K1><<<gbig, blk, 0, stream>>>(h0b + (size_t)B * H, wh1b, Zh, G, stats + 6 * G, stats + 7 * G);
  coef_k<<<G / 256, 256, 0, stream>>>(stats + 4 * G, gx1, bx1, gh1, bh1, coef + 3 * G, 1.f / B);
  cell_k<<<B, 256, 0, stream>>>(Zx, Zh, coef + 3 * G, c0 + (size_t)B * H,
                                h_o + (size_t)B * H, c_o + (size_t)B * H, h1b);

  // output projection (old kernel: N=256 grid = (2,128))
  const dim3 gout(NOUT / 128, B / 128);
  gemm_bt<0, 1><<<gout, blk, 0, stream>>>(h1b, wob, out_o, NOUT, K1, nullptr, nullptr, bo);
}

// Round 3
// 540.547 us; speedup vs baseline: 1.1818x; 1.1115x over previous
//
#include <hip/hip_runtime.h>
#include <cstdint>

typedef unsigned short u16;
typedef unsigned int u32;
typedef float floatx4 __attribute__((ext_vector_type(4)));
typedef __bf16 bf16x8 __attribute__((ext_vector_type(8)));
typedef u16 u16x4 __attribute__((ext_vector_type(4)));

__device__ __forceinline__ u16 f2b(float f) {
  u32 u = __builtin_bit_cast(u32, f);
  u32 r = (u + 0x7fffu + ((u >> 16) & 1u)) >> 16;
  return (u16)r;
}
__device__ __forceinline__ float b2f(u16 b) {
  return __builtin_bit_cast(float, (u32)b << 16);
}
// packed 2xf32 -> 2xbf16 (RNE, bit-identical to f2b for normal values)
__device__ __forceinline__ u32 pkbf(float lo, float hi) {
  u32 r;
  asm("v_cvt_pk_bf16_f32 %0, %1, %2" : "=v"(r) : "v"(lo), "v"(hi));
  return r;
}
__device__ __forceinline__ float sigf(float x) { return 1.f / (1.f + __expf(-x)); }
__device__ __forceinline__ float tanhfast(float x) { return 2.f / (1.f + __expf(-2.f * x)) - 1.f; }

#define GLDS(gp, lp) __builtin_amdgcn_global_load_lds( \
    (const __attribute__((address_space(1))) u32*)(gp), \
    (__attribute__((address_space(3))) u32*)(lp), 16, 0, 0)

// ============================================================================
// 128x128-tile GEMM body, BK=32, 3-slot circular LDS pipeline, counted vmcnt.
// C32: row-pair packed bf16 output: u32 at [(row>>1)*N + col], lo16 = even row.
// Stats: per-column sum/sumsq atomics.
// ============================================================================
template <int KT>
__device__ __forceinline__ void gemm_body(
    const u16* __restrict__ A, const u16* __restrict__ W, u32* __restrict__ C32,
    int N, float* __restrict__ ssum, float* __restrict__ ssq, u16* lds) {
  constexpr int NT = KT / 32;
  const int tid = threadIdx.x;
  const int lane = tid & 63;
  const int wid = tid >> 6;
  const int wm = (wid >> 1) << 6;
  const int wn = (wid & 1) << 6;
  const int fr = lane & 15;
  const int fq = lane >> 4;

  // XCD-chunked bijective remap over the (16, M/128) slice.
  const int l = blockIdx.x + (blockIdx.y << 4);
  const int xcd = l & 7;
  const int idx = l >> 3;
  const int bx = idx & 15;
  const int by = (xcd << 4) + (idx >> 4);
  const int m0 = by << 7;
  const int n0 = bx << 7;

  const u16* Ab = A + (size_t)m0 * KT;
  const u16* Wb = W + (size_t)n0 * KT;

  const int ra = tid >> 2;
  const int ca = (tid & 3) ^ ((ra >> 1) & 3);
  const u16* pa0 = Ab + (size_t)ra * KT + ca * 8;
  const u16* pa1 = pa0 + (size_t)64 * KT;
  const u16* pb0 = Wb + (size_t)ra * KT + ca * 8;
  const u16* pb1 = pb0 + (size_t)64 * KT;
  const int da = tid * 8;
  const int db = 4096 + tid * 8;

#define STAGE(kt) do {                                   \
    const int _sl = ((kt) % 3) * 8192;                   \
    const int _ko = (kt) * 32;                           \
    GLDS(pa0 + _ko, &lds[_sl + da]);                     \
    GLDS(pa1 + _ko, &lds[_sl + da + 2048]);              \
    GLDS(pb0 + _ko, &lds[_sl + db]);                     \
    GLDS(pb1 + _ko, &lds[_sl + db + 2048]);              \
  } while (0)

  int aoffs[4], boffs[4];
#pragma unroll
  for (int mf = 0; mf < 4; ++mf) {
    const int R = wm + mf * 16 + fr;
    aoffs[mf] = R * 32 + ((fq ^ ((R >> 1) & 3)) << 3);
  }
#pragma unroll
  for (int nf = 0; nf < 4; ++nf) {
    const int R = wn + nf * 16 + fr;
    boffs[nf] = 4096 + R * 32 + ((fq ^ ((R >> 1) & 3)) << 3);
  }

  floatx4 acc[4][4] = {};

  STAGE(0);
  STAGE(1);

#pragma unroll
  for (int t = 0; t < NT; ++t) {
    if (t == NT - 1) asm volatile("s_waitcnt vmcnt(0)" ::: "memory");
    else             asm volatile("s_waitcnt vmcnt(4)" ::: "memory");
    __builtin_amdgcn_s_barrier();
    __builtin_amdgcn_sched_barrier(0);

    if (t + 2 < NT) STAGE(t + 2);

    const int sl = (t % 3) * 8192;
    bf16x8 bfv[4];
#pragma unroll
    for (int nf = 0; nf < 4; ++nf) bfv[nf] = *(const bf16x8*)&lds[sl + boffs[nf]];
    __builtin_amdgcn_s_setprio(1);
#pragma unroll
    for (int mf = 0; mf < 4; ++mf) {
      const bf16x8 af = *(const bf16x8*)&lds[sl + aoffs[mf]];
#pragma unroll
      for (int nf = 0; nf < 4; ++nf)
        acc[mf][nf] = __builtin_amdgcn_mfma_f32_16x16x32_bf16(af, bfv[nf], acc[mf][nf], 0, 0, 0);
    }
    __builtin_amdgcn_s_setprio(0);
    asm volatile("s_waitcnt lgkmcnt(0)" ::: "memory");
    __builtin_amdgcn_sched_barrier(0);
  }
#undef STAGE

  // Epilogue: packed row-pair stores (cvt_pk) + per-column stats.
#pragma unroll
  for (int mf = 0; mf < 4; ++mf) {
    const int rp = (m0 + wm + mf * 16 + fq * 4) >> 1;  // even base
#pragma unroll
    for (int nf = 0; nf < 4; ++nf) {
      const int col = n0 + wn + nf * 16 + fr;
#pragma unroll
      for (int p = 0; p < 2; ++p)
        C32[(size_t)(rp + p) * N + col] = pkbf(acc[mf][nf][2 * p], acc[mf][nf][2 * p + 1]);
    }
  }
#pragma unroll
  for (int nf = 0; nf < 4; ++nf) {
    float s = 0.f, qv = 0.f;
#pragma unroll
    for (int mf = 0; mf < 4; ++mf)
#pragma unroll
      for (int r = 0; r < 4; ++r) {
        const float v = acc[mf][nf][r];
        s += v;
        qv += v * v;
      }
    s += __shfl_xor(s, 16);
    s += __shfl_xor(s, 32);
    qv += __shfl_xor(qv, 16);
    qv += __shfl_xor(qv, 32);
    if (fq == 0) {
      atomicAdd(&ssum[n0 + wn + nf * 16 + fr], s);
      atomicAdd(&ssq[n0 + wn + nf * 16 + fr], qv);
    }
  }
}

// Two independent GEMMs (same M,N) in one dispatch; grid.z selects.
template <int KTX, int KTH>
__global__ __launch_bounds__(256) void gemm_pair(
    const u16* __restrict__ Ax, const u16* __restrict__ Wx, u32* __restrict__ Cx,
    float* __restrict__ ssx, float* __restrict__ sqx,
    const u16* __restrict__ Ah, const u16* __restrict__ Wh, u32* __restrict__ Ch,
    float* __restrict__ ssh, float* __restrict__ sqh, int N) {
  __shared__ __align__(16) u16 lds[3 * 8192];
  if (blockIdx.z == 0) gemm_body<KTX>(Ax, Wx, Cx, N, ssx, sqx, lds);
  else                 gemm_body<KTH>(Ah, Wh, Ch, N, ssh, sqh, lds);
}

// ============================================================================
// Output projection: old 2-barrier 128x128 kernel, fp32 + bias epilogue.
// ============================================================================
__global__ __launch_bounds__(256) void gemm_out(
    const u16* __restrict__ A, const u16* __restrict__ W, float* __restrict__ C,
    int N, int K, const float* __restrict__ bias) {
  __shared__ u16 As[128 * 32];
  __shared__ u16 Bs[128 * 32];
  const int tid = threadIdx.x;
  const int lane = tid & 63;
  const int wave = tid >> 6;
  const int wm = (wave >> 1) << 6;
  const int wn = (wave & 1) << 6;
  const int m0 = blockIdx.y * 128;
  const int n0 = blockIdx.x * 128;
  const u16* Ab = A + (size_t)m0 * K;
  const u16* Wb = W + (size_t)n0 * K;
  const size_t soff = (size_t)(tid >> 2) * K + ((tid & 3) << 3);
  const size_t soff2 = soff + (size_t)64 * K;
  const int fr = lane & 15;
  const int fq = lane >> 4;
  const int aoff = fr * 32 + fq * 8;

  floatx4 acc[4][4] = {};

  for (int k0 = 0; k0 < K; k0 += 32) {
    __syncthreads();
    GLDS(Ab + soff + k0, &As[tid * 8]);
    GLDS(Ab + soff2 + k0, &As[tid * 8 + 2048]);
    GLDS(Wb + soff + k0, &Bs[tid * 8]);
    GLDS(Wb + soff2 + k0, &Bs[tid * 8 + 2048]);
    __syncthreads();
    bf16x8 af[4], bfv[4];
#pragma unroll
    for (int i = 0; i < 4; ++i) af[i] = *(const bf16x8*)&As[(wm + i * 16) * 32 + aoff];
#pragma unroll
    for (int j = 0; j < 4; ++j) bfv[j] = *(const bf16x8*)&Bs[(wn + j * 16) * 32 + aoff];
#pragma unroll
    for (int i = 0; i < 4; ++i)
#pragma unroll
      for (int j = 0; j < 4; ++j)
        acc[i][j] = __builtin_amdgcn_mfma_f32_16x16x32_bf16(af[i], bfv[j], acc[i][j], 0, 0, 0);
  }

#pragma unroll
  for (int i = 0; i < 4; ++i)
#pragma unroll
    for (int j = 0; j < 4; ++j) {
      const int col = n0 + wn + j * 16 + fr;
      const float bv = bias[col];
#pragma unroll
      for (int r = 0; r < 4; ++r) {
        const int row = m0 + wm + i * 16 + fq * 4 + r;
        C[(size_t)row * N + col] = acc[i][j][r] + bv;
      }
    }
}

// ============================================================================
// Prep kernels (merged)
// ============================================================================
// seg0 (4608 blocks): concat [x|y|0] -> bf16 [B,288], float4-vectorized
// seg1 (16384 blocks): h0 f32 -> bf16 (2*B*H elems)
__global__ void prep_inputs_k(const float* __restrict__ x, const float* __restrict__ y,
                              u16* __restrict__ inpb,
                              const float4* __restrict__ h0, u16x4* __restrict__ h0b) {
  const int bid = blockIdx.x;
  if (bid < 4608) {
    const int idx = bid * 256 + threadIdx.x;  // B*72
    const int b = idx / 72;
    const int c4 = idx - b * 72;
    float4 v = make_float4(0.f, 0.f, 0.f, 0.f);
    if (c4 < 64) v = ((const float4*)x)[b * 64 + c4];
    else if (c4 == 64) v.x = y[b];
    u16x4 r;
    r.x = f2b(v.x); r.y = f2b(v.y); r.z = f2b(v.z); r.w = f2b(v.w);
    *(u16x4*)&inpb[b * 288 + c4 * 4] = r;
  } else {
    const int idx = (bid - 4608) * 256 + threadIdx.x;  // 2*B*H/4
    const float4 v = h0[idx];
    u16x4 r;
    r.x = f2b(v.x); r.y = f2b(v.y); r.z = f2b(v.z); r.w = f2b(v.w);
    h0b[idx] = r;
  }
}

// seg0 (2304 blocks): Wx0 [2048,257] -> bf16 [2048,288] zero-padded (scalar)
// seg1-3 (1024 each): Wh0, Wx1, Wh1 f2b (f4)
// seg4 (128): Wo f2b (f4)
__global__ void prep_weights_k(
    const float* __restrict__ Wx0, u16* __restrict__ wx0b,
    const float4* __restrict__ Wh0, u16x4* __restrict__ wh0b,
    const float4* __restrict__ Wx1, u16x4* __restrict__ wx1b,
    const float4* __restrict__ Wh1, u16x4* __restrict__ wh1b,
    const float4* __restrict__ Wo, u16x4* __restrict__ wob) {
  const int bid = blockIdx.x;
  if (bid < 2304) {
    const int idx = bid * 256 + threadIdx.x;  // 2048*288
    const int r = idx / 288;
    const int c = idx - r * 288;
    wx0b[idx] = f2b(c < 257 ? Wx0[r * 257 + c] : 0.f);
    return;
  }
  const float4* src;
  u16x4* dst;
  int idx;
  if (bid < 2304 + 3072) {
    const int seg = (bid - 2304) >> 10;          // 0,1,2
    idx = ((bid - 2304) & 1023) * 256 + threadIdx.x;
    src = seg == 0 ? Wh0 : (seg == 1 ? Wx1 : Wh1);
    dst = seg == 0 ? wh0b : (seg == 1 ? wx1b : wh1b);
  } else {
    idx = (bid - 2304 - 3072) * 256 + threadIdx.x;
    src = Wo;
    dst = wob;
  }
  const float4 v = src[idx];
  u16x4 r;
  r.x = f2b(v.x); r.y = f2b(v.y); r.z = f2b(v.z); r.w = f2b(v.w);
  dst[idx] = r;
}

// stats layout per layer: [sum_x, sq_x, sum_h, sq_h] each 2048
// coef layout per layer:  [ax, ah, cb] each 2048
__global__ void coef_k(const float* __restrict__ st, const float* __restrict__ gx,
                       const float* __restrict__ bx, const float* __restrict__ gh,
                       const float* __restrict__ bh, float* __restrict__ cf, float invB) {
  const int j = blockIdx.x * 256 + threadIdx.x;  // 2048
  const float mx = st[j] * invB;
  const float vx = st[2048 + j] * invB - mx * mx;
  const float ax = gx[j] * rsqrtf(vx + 1e-5f);
  const float mh = st[4096 + j] * invB;
  const float vh = st[6144 + j] * invB - mh * mh;
  const float ah = gh[j] * rsqrtf(vh + 1e-5f);
  cf[j] = ax;
  cf[2048 + j] = ah;
  cf[4096 + j] = bx[j] - mx * ax + bh[j] - mh * ah;
}

// fused BN-affine + LSTM cell on row-pair packed Z.
// thread -> (batch-pair bp, col-pair j2): 4 cells (2 batches x 2 cols).
__global__ __launch_bounds__(256) void cell2_k(
    const u32* __restrict__ Zx, const u32* __restrict__ Zh,
    const float* __restrict__ coef, const float* __restrict__ cin,
    float* __restrict__ hout, float* __restrict__ cout, u16* __restrict__ hb) {
  const int idx = blockIdx.x * 256 + threadIdx.x;  // (B/2)*256
  const int bp = idx >> 8;
  const int j2 = (idx & 255) << 1;
  const size_t zb = (size_t)bp << 11;  // bp*2048 (u32 row-pair stride)
  float gv[4][2][2];  // [gate][batch-sel][col-sel]
#pragma unroll
  for (int g = 0; g < 4; ++g) {
    const int col = (g << 9) + j2;
    const uint2 zx2 = *(const uint2*)&Zx[zb + col];
    const uint2 zh2 = *(const uint2*)&Zh[zb + col];
    const float2 ax = *(const float2*)&coef[col];
    const float2 ah = *(const float2*)&coef[2048 + col];
    const float2 cb = *(const float2*)&coef[4096 + col];
    gv[g][0][0] = ax.x * b2f((u16)zx2.x) + ah.x * b2f((u16)zh2.x) + cb.x;
    gv[g][1][0] = ax.x * b2f((u16)(zx2.x >> 16)) + ah.x * b2f((u16)(zh2.x >> 16)) + cb.x;
    gv[g][0][1] = ax.y * b2f((u16)zx2.y) + ah.y * b2f((u16)zh2.y) + cb.y;
    gv[g][1][1] = ax.y * b2f((u16)(zx2.y >> 16)) + ah.y * b2f((u16)(zh2.y >> 16)) + cb.y;
  }
#pragma unroll
  for (int s = 0; s < 2; ++s) {
    const int b = (bp << 1) + s;
    const size_t ob = ((size_t)b << 9) + j2;
    const float2 cp = *(const float2*)(cin + ob);
    float cn[2], hn[2];
#pragma unroll
    for (int t = 0; t < 2; ++t) {
      const float cprev = t ? cp.y : cp.x;
      const float cc = sigf(gv[0][s][t]) * cprev + sigf(gv[1][s][t]) * tanhfast(gv[3][s][t]);
      cn[t] = cc;
      hn[t] = sigf(gv[2][s][t]) * tanhfast(cc);
    }
    *(float2*)(cout + ob) = make_float2(cn[0], cn[1]);
    *(float2*)(hout + ob) = make_float2(hn[0], hn[1]);
    *(u32*)(hb + ob) = pkbf(hn[0], hn[1]);
  }
}

extern "C" void kernel_launch(void* const* d_in, const int* in_sizes, int n_in,
                              void* d_out, int out_size, void* d_ws, size_t ws_size,
                              hipStream_t stream) {
  (void)in_sizes; (void)n_in; (void)out_size; (void)ws_size;
  constexpr int B = 16384, H = 512, G = 2048, KP = 288, K1 = 512, NOUT = 256;

  const float* x = (const float*)d_in[0];
  const float* y = (const float*)d_in[1];
  const float* h0 = (const float*)d_in[2];
  const float* c0 = (const float*)d_in[3];
  const float* Wx0 = (const float*)d_in[4];
  const float* Wh0 = (const float*)d_in[5];
  const float* gx0 = (const float*)d_in[6];
  const float* bx0 = (const float*)d_in[7];
  const float* gh0 = (const float*)d_in[8];
  const float* bh0 = (const float*)d_in[9];
  const float* Wx1 = (const float*)d_in[10];
  const float* Wh1 = (const float*)d_in[11];
  const float* gx1 = (const float*)d_in[12];
  const float* bx1 = (const float*)d_in[13];
  const float* gh1 = (const float*)d_in[14];
  const float* bh1 = (const float*)d_in[15];
  const float* Wo = (const float*)d_in[16];
  const float* bo = (const float*)d_in[17];

  char* p = (char*)d_ws;
  u16* Zx = (u16*)p;   p += (size_t)B * G * 2;
  u16* Zh = (u16*)p;   p += (size_t)B * G * 2;
  u16* h0b = (u16*)p;  p += (size_t)2 * B * H * 2;
  u16* h1b = (u16*)p;  p += (size_t)B * H * 2;   // reused for h2 bf16
  u16* inpb = (u16*)p; p += (size_t)B * KP * 2;
  u16* wx0b = (u16*)p; p += (size_t)G * KP * 2;
  u16* wh0b = (u16*)p; p += (size_t)G * K1 * 2;
  u16* wx1b = (u16*)p; p += (size_t)G * K1 * 2;
  u16* wh1b = (u16*)p; p += (size_t)G * K1 * 2;
  u16* wob = (u16*)p;  p += (size_t)NOUT * K1 * 2;
  float* stats = (float*)p; p += (size_t)8 * G * 4;
  float* coef = (float*)p;  p += (size_t)6 * G * 4;

  float* out_o = (float*)d_out;                     // [B,256]
  float* h_o = out_o + (size_t)B * NOUT;            // [2,B,512]
  float* c_o = h_o + (size_t)2 * B * H;             // [2,B,512]

  hipMemsetAsync(stats, 0, (size_t)8 * G * sizeof(float), stream);

  prep_inputs_k<<<4608 + 16384, 256, 0, stream>>>(x, y, inpb, (const float4*)h0, (u16x4*)h0b);
  prep_weights_k<<<2304 + 3072 + 128, 256, 0, stream>>>(
      Wx0, wx0b, (const float4*)Wh0, (u16x4*)wh0b, (const float4*)Wx1, (u16x4*)wx1b,
      (const float4*)Wh1, (u16x4*)wh1b, (const float4*)Wo, (u16x4*)wob);

  const dim3 blk(256);
  const dim3 gpair(G / 128, B / 128, 2);  // (16, 128, 2)

  // layer 0
  gemm_pair<KP, K1><<<gpair, blk, 0, stream>>>(
      inpb, wx0b, (u32*)Zx, stats + 0 * G, stats + 1 * G,
      h0b, wh0b, (u32*)Zh, stats + 2 * G, stats + 3 * G, G);
  coef_k<<<G / 256, 256, 0, stream>>>(stats, gx0, bx0, gh0, bh0, coef, 1.f / B);
  cell2_k<<<B / 2, 256, 0, stream>>>((const u32*)Zx, (const u32*)Zh, coef, c0, h_o, c_o, h1b);

  // layer 1
  gemm_pair<K1, K1><<<gpair, blk, 0, stream>>>(
      h1b, wx1b, (u32*)Zx, stats + 4 * G, stats + 5 * G,
      h0b + (size_t)B * H, wh1b, (u32*)Zh, stats + 6 * G, stats + 7 * G, G);
  coef_k<<<G / 256, 256, 0, stream>>>(stats + 4 * G, gx1, bx1, gh1, bh1, coef + 3 * G, 1.f / B);
  cell2_k<<<B / 2, 256, 0, stream>>>((const u32*)Zx, (const u32*)Zh, coef + 3 * G,
                                     c0 + (size_t)B * H, h_o + (size_t)B * H,
                                     c_o + (size_t)B * H, h1b);

  // output projection
  const dim3 gout(NOUT / 128, B / 128);
  gemm_out<<<gout, blk, 0, stream>>>(h1b, wob, out_o, NOUT, K1, bo);
}

// Round 4
// 528.043 us; speedup vs baseline: 1.2098x; 1.0237x over previous
//
#include <hip/hip_runtime.h>
#include <cstdint>

typedef unsigned short u16;
typedef unsigned int u32;
typedef float floatx4 __attribute__((ext_vector_type(4)));
typedef __bf16 bf16x8 __attribute__((ext_vector_type(8)));
typedef u16 u16x4 __attribute__((ext_vector_type(4)));

__device__ __forceinline__ u16 f2b(float f) {
  u32 u = __builtin_bit_cast(u32, f);
  u32 r = (u + 0x7fffu + ((u >> 16) & 1u)) >> 16;
  return (u16)r;
}
__device__ __forceinline__ float b2f(u16 b) {
  return __builtin_bit_cast(float, (u32)b << 16);
}
// packed 2xf32 -> 2xbf16 (RNE, bit-identical to f2b for normal values)
__device__ __forceinline__ u32 pkbf(float lo, float hi) {
  u32 r;
  asm("v_cvt_pk_bf16_f32 %0, %1, %2" : "=v"(r) : "v"(lo), "v"(hi));
  return r;
}
__device__ __forceinline__ float sigf(float x) { return 1.f / (1.f + __expf(-x)); }
__device__ __forceinline__ float tanhfast(float x) { return 2.f / (1.f + __expf(-2.f * x)) - 1.f; }

#define GLDS(gp, lp) __builtin_amdgcn_global_load_lds( \
    (const __attribute__((address_space(1))) u32*)(gp), \
    (__attribute__((address_space(3))) u32*)(lp), 16, 0, 0)

// ============================================================================
// 128(M)x256(N)-tile GEMM body, 8 waves (wave-tile 64x64), BK=32,
// 3-slot circular LDS (72KB -> 2 blocks/CU), counted vmcnt.
// C32: row-pair packed bf16: u32 at [(row>>1)*N + col], lo16 = even row.
// Stats: per-column sum/sumsq atomics, sharded by XCD (shard stride 2048).
// Grid: (8, M/128, z); XCD-chunked remap baked in.
// ============================================================================
template <int KT>
__device__ __forceinline__ void gemm_body(
    const u16* __restrict__ A, const u16* __restrict__ W, u32* __restrict__ C32,
    int N, float* __restrict__ ssum, float* __restrict__ ssq, u16* lds) {
  constexpr int NT = KT / 32;
  constexpr int SLOT = 12288;  // u16 per slot: A 4096 (8KB) + B 8192 (16KB)
  const int tid = threadIdx.x;
  const int lane = tid & 63;
  const int wid = tid >> 6;        // 0..7
  const int wm = (wid >> 2) << 6;  // 0 / 64
  const int wn = (wid & 3) << 6;   // 0 / 64 / 128 / 192
  const int fr = lane & 15;
  const int fq = lane >> 4;

  // XCD-chunked bijective remap: 1024 blocks/z, 128 per XCD.
  const int l = blockIdx.x + (blockIdx.y << 3);
  const int xcd = l & 7;
  const int idx = l >> 3;          // 0..127
  const int bx = idx & 7;          // 8 n-blocks
  const int by = (xcd << 4) + (idx >> 3);  // 128 m-blocks, chunked per XCD
  const int m0 = by << 7;
  const int n0 = bx << 8;

  const u16* Ab = A + (size_t)m0 * KT;
  const u16* Wb = W + (size_t)n0 * KT;

  // Staging: 16B chunks. A: 512 chunks (128 rows x 4) -> 1/thread.
  // B: 1024 chunks (256 rows x 4) -> 2/thread (q=tid, q=tid+512; same swizzle
  // col since (r+128)>>1 keeps (..&3)). chunk q: r=q>>2, c=(q&3)^((r>>1)&3).
  const int ra = tid >> 2;
  const int ca = (tid & 3) ^ ((ra >> 1) & 3);
  const u16* pa0 = Ab + (size_t)ra * KT + ca * 8;
  const u16* pb0 = Wb + (size_t)ra * KT + ca * 8;
  const u16* pb1 = pb0 + (size_t)128 * KT;
  const int da = tid * 8;          // A dest u16 idx (0..4088)
  const int db = 4096 + tid * 8;   // B dest; second chunk +4096

#define STAGE(kt) do {                                   \
    const int _sl = ((kt) % 3) * SLOT;                   \
    const int _ko = (kt) * 32;                           \
    GLDS(pa0 + _ko, &lds[_sl + da]);                     \
    GLDS(pb0 + _ko, &lds[_sl + db]);                     \
    GLDS(pb1 + _ko, &lds[_sl + db + 4096]);              \
  } while (0)

  // ds_read offsets (u16 idx within slot); swizzle matches staging.
  int aoffs[4], boffs[4];
#pragma unroll
  for (int mf = 0; mf < 4; ++mf) {
    const int R = wm + mf * 16 + fr;                 // 0..127
    aoffs[mf] = R * 32 + ((fq ^ ((R >> 1) & 3)) << 3);
  }
#pragma unroll
  for (int nf = 0; nf < 4; ++nf) {
    const int R = wn + nf * 16 + fr;                 // 0..255
    boffs[nf] = 4096 + R * 32 + ((fq ^ ((R >> 1) & 3)) << 3);
  }

  floatx4 acc[4][4] = {};

  STAGE(0);
  STAGE(1);

#pragma unroll
  for (int t = 0; t < NT; ++t) {
    // Drain tile t's 3 loads; keep tile t+1's 3 in flight.
    if (t == NT - 1) asm volatile("s_waitcnt vmcnt(0)" ::: "memory");
    else             asm volatile("s_waitcnt vmcnt(3)" ::: "memory");
    __builtin_amdgcn_s_barrier();
    __builtin_amdgcn_sched_barrier(0);

    if (t + 2 < NT) STAGE(t + 2);  // slot (t+2)%3 == (t-1)%3: freed by last
                                   // iter's lgkmcnt(0) + this barrier

    const int sl = (t % 3) * SLOT;
    bf16x8 bfv[4];
#pragma unroll
    for (int nf = 0; nf < 4; ++nf) bfv[nf] = *(const bf16x8*)&lds[sl + boffs[nf]];
    __builtin_amdgcn_s_setprio(1);
#pragma unroll
    for (int mf = 0; mf < 4; ++mf) {
      const bf16x8 af = *(const bf16x8*)&lds[sl + aoffs[mf]];
#pragma unroll
      for (int nf = 0; nf < 4; ++nf)
        acc[mf][nf] = __builtin_amdgcn_mfma_f32_16x16x32_bf16(af, bfv[nf], acc[mf][nf], 0, 0, 0);
    }
    __builtin_amdgcn_s_setprio(0);
    asm volatile("s_waitcnt lgkmcnt(0)" ::: "memory");
    __builtin_amdgcn_sched_barrier(0);
  }
#undef STAGE

  // Epilogue: packed row-pair stores (cvt_pk) + per-column stats (XCD shard).
#pragma unroll
  for (int mf = 0; mf < 4; ++mf) {
    const int rp = (m0 + wm + mf * 16 + fq * 4) >> 1;
#pragma unroll
    for (int nf = 0; nf < 4; ++nf) {
      const int col = n0 + wn + nf * 16 + fr;
#pragma unroll
      for (int p = 0; p < 2; ++p)
        C32[(size_t)(rp + p) * N + col] = pkbf(acc[mf][nf][2 * p], acc[mf][nf][2 * p + 1]);
    }
  }
  float* ss = ssum + xcd * 2048;
  float* sq = ssq + xcd * 2048;
#pragma unroll
  for (int nf = 0; nf < 4; ++nf) {
    float s = 0.f, qv = 0.f;
#pragma unroll
    for (int mf = 0; mf < 4; ++mf)
#pragma unroll
      for (int r = 0; r < 4; ++r) {
        const float v = acc[mf][nf][r];
        s += v;
        qv += v * v;
      }
    s += __shfl_xor(s, 16);
    s += __shfl_xor(s, 32);
    qv += __shfl_xor(qv, 16);
    qv += __shfl_xor(qv, 32);
    if (fq == 0) {
      atomicAdd(&ss[n0 + wn + nf * 16 + fr], s);
      atomicAdd(&sq[n0 + wn + nf * 16 + fr], qv);
    }
  }
}

// Two independent GEMMs (same M,N) in one dispatch; grid.z selects.
template <int KTX, int KTH>
__global__ __launch_bounds__(512, 4) void gemm_pair(
    const u16* __restrict__ Ax, const u16* __restrict__ Wx, u32* __restrict__ Cx,
    float* __restrict__ ssx, float* __restrict__ sqx,
    const u16* __restrict__ Ah, const u16* __restrict__ Wh, u32* __restrict__ Ch,
    float* __restrict__ ssh, float* __restrict__ sqh, int N) {
  __shared__ __align__(16) u16 lds[3 * 12288];  // 72 KB
  if (blockIdx.z == 0) gemm_body<KTX>(Ax, Wx, Cx, N, ssx, sqx, lds);
  else                 gemm_body<KTH>(Ah, Wh, Ch, N, ssh, sqh, lds);
}

// ============================================================================
// Output projection: old 2-barrier 128x128 kernel, fp32 + bias epilogue.
// ============================================================================
__global__ __launch_bounds__(256) void gemm_out(
    const u16* __restrict__ A, const u16* __restrict__ W, float* __restrict__ C,
    int N, int K, const float* __restrict__ bias) {
  __shared__ u16 As[128 * 32];
  __shared__ u16 Bs[128 * 32];
  const int tid = threadIdx.x;
  const int lane = tid & 63;
  const int wave = tid >> 6;
  const int wm = (wave >> 1) << 6;
  const int wn = (wave & 1) << 6;
  const int m0 = blockIdx.y * 128;
  const int n0 = blockIdx.x * 128;
  const u16* Ab = A + (size_t)m0 * K;
  const u16* Wb = W + (size_t)n0 * K;
  const size_t soff = (size_t)(tid >> 2) * K + ((tid & 3) << 3);
  const size_t soff2 = soff + (size_t)64 * K;
  const int fr = lane & 15;
  const int fq = lane >> 4;
  const int aoff = fr * 32 + fq * 8;

  floatx4 acc[4][4] = {};

  for (int k0 = 0; k0 < K; k0 += 32) {
    __syncthreads();
    GLDS(Ab + soff + k0, &As[tid * 8]);
    GLDS(Ab + soff2 + k0, &As[tid * 8 + 2048]);
    GLDS(Wb + soff + k0, &Bs[tid * 8]);
    GLDS(Wb + soff2 + k0, &Bs[tid * 8 + 2048]);
    __syncthreads();
    bf16x8 af[4], bfv[4];
#pragma unroll
    for (int i = 0; i < 4; ++i) af[i] = *(const bf16x8*)&As[(wm + i * 16) * 32 + aoff];
#pragma unroll
    for (int j = 0; j < 4; ++j) bfv[j] = *(const bf16x8*)&Bs[(wn + j * 16) * 32 + aoff];
#pragma unroll
    for (int i = 0; i < 4; ++i)
#pragma unroll
      for (int j = 0; j < 4; ++j)
        acc[i][j] = __builtin_amdgcn_mfma_f32_16x16x32_bf16(af[i], bfv[j], acc[i][j], 0, 0, 0);
  }

#pragma unroll
  for (int i = 0; i < 4; ++i)
#pragma unroll
    for (int j = 0; j < 4; ++j) {
      const int col = n0 + wn + j * 16 + fr;
      const float bv = bias[col];
#pragma unroll
      for (int r = 0; r < 4; ++r) {
        const int row = m0 + wm + i * 16 + fq * 4 + r;
        C[(size_t)row * N + col] = acc[i][j][r] + bv;
      }
    }
}

// ============================================================================
// Prep kernels (merged)
// ============================================================================
__global__ void prep_inputs_k(const float* __restrict__ x, const float* __restrict__ y,
                              u16* __restrict__ inpb,
                              const float4* __restrict__ h0, u16x4* __restrict__ h0b) {
  const int bid = blockIdx.x;
  if (bid < 4608) {
    const int idx = bid * 256 + threadIdx.x;  // B*72
    const int b = idx / 72;
    const int c4 = idx - b * 72;
    float4 v = make_float4(0.f, 0.f, 0.f, 0.f);
    if (c4 < 64) v = ((const float4*)x)[b * 64 + c4];
    else if (c4 == 64) v.x = y[b];
    u16x4 r;
    r.x = f2b(v.x); r.y = f2b(v.y); r.z = f2b(v.z); r.w = f2b(v.w);
    *(u16x4*)&inpb[b * 288 + c4 * 4] = r;
  } else {
    const int idx = (bid - 4608) * 256 + threadIdx.x;  // 2*B*H/4
    const float4 v = h0[idx];
    u16x4 r;
    r.x = f2b(v.x); r.y = f2b(v.y); r.z = f2b(v.z); r.w = f2b(v.w);
    h0b[idx] = r;
  }
}

__global__ void prep_weights_k(
    const float* __restrict__ Wx0, u16* __restrict__ wx0b,
    const float4* __restrict__ Wh0, u16x4* __restrict__ wh0b,
    const float4* __restrict__ Wx1, u16x4* __restrict__ wx1b,
    const float4* __restrict__ Wh1, u16x4* __restrict__ wh1b,
    const float4* __restrict__ Wo, u16x4* __restrict__ wob) {
  const int bid = blockIdx.x;
  if (bid < 2304) {
    const int idx = bid * 256 + threadIdx.x;  // 2048*288
    const int r = idx / 288;
    const int c = idx - r * 288;
    wx0b[idx] = f2b(c < 257 ? Wx0[r * 257 + c] : 0.f);
    return;
  }
  const float4* src;
  u16x4* dst;
  int idx;
  if (bid < 2304 + 3072) {
    const int seg = (bid - 2304) >> 10;
    idx = ((bid - 2304) & 1023) * 256 + threadIdx.x;
    src = seg == 0 ? Wh0 : (seg == 1 ? Wx1 : Wh1);
    dst = seg == 0 ? wh0b : (seg == 1 ? wx1b : wh1b);
  } else {
    idx = (bid - 2304 - 3072) * 256 + threadIdx.x;
    src = Wo;
    dst = wob;
  }
  const float4 v = src[idx];
  u16x4 r;
  r.x = f2b(v.x); r.y = f2b(v.y); r.z = f2b(v.z); r.w = f2b(v.w);
  dst[idx] = r;
}

// stats: per layer 4 logical arrays [sum_x, sq_x, sum_h, sq_h], each 8 XCD
// shards x 2048 (stride SH=16384 floats between arrays).
// coef layout per layer: [ax, ah, cb] each 2048
__global__ void coef_k(const float* __restrict__ st, const float* __restrict__ gx,
                       const float* __restrict__ bx, const float* __restrict__ gh,
                       const float* __restrict__ bh, float* __restrict__ cf, float invB) {
  constexpr int SH = 8 * 2048;
  const int j = blockIdx.x * 256 + threadIdx.x;  // 2048
  float sx = 0.f, qx = 0.f, sh = 0.f, qh = 0.f;
#pragma unroll
  for (int s = 0; s < 8; ++s) {
    sx += st[0 * SH + s * 2048 + j];
    qx += st[1 * SH + s * 2048 + j];
    sh += st[2 * SH + s * 2048 + j];
    qh += st[3 * SH + s * 2048 + j];
  }
  const float mx = sx * invB;
  const float vx = qx * invB - mx * mx;
  const float ax = gx[j] * rsqrtf(vx + 1e-5f);
  const float mh = sh * invB;
  const float vh = qh * invB - mh * mh;
  const float ah = gh[j] * rsqrtf(vh + 1e-5f);
  cf[j] = ax;
  cf[2048 + j] = ah;
  cf[4096 + j] = bx[j] - mx * ax + bh[j] - mh * ah;
}

// fused BN-affine + LSTM cell on row-pair packed Z.
__global__ __launch_bounds__(256) void cell2_k(
    const u32* __restrict__ Zx, const u32* __restrict__ Zh,
    const float* __restrict__ coef, const float* __restrict__ cin,
    float* __restrict__ hout, float* __restrict__ cout, u16* __restrict__ hb) {
  const int idx = blockIdx.x * 256 + threadIdx.x;  // (B/2)*256
  const int bp = idx >> 8;
  const int j2 = (idx & 255) << 1;
  const size_t zb = (size_t)bp << 11;
  float gv[4][2][2];
#pragma unroll
  for (int g = 0; g < 4; ++g) {
    const int col = (g << 9) + j2;
    const uint2 zx2 = *(const uint2*)&Zx[zb + col];
    const uint2 zh2 = *(const uint2*)&Zh[zb + col];
    const float2 ax = *(const float2*)&coef[col];
    const float2 ah = *(const float2*)&coef[2048 + col];
    const float2 cb = *(const float2*)&coef[4096 + col];
    gv[g][0][0] = ax.x * b2f((u16)zx2.x) + ah.x * b2f((u16)zh2.x) + cb.x;
    gv[g][1][0] = ax.x * b2f((u16)(zx2.x >> 16)) + ah.x * b2f((u16)(zh2.x >> 16)) + cb.x;
    gv[g][0][1] = ax.y * b2f((u16)zx2.y) + ah.y * b2f((u16)zh2.y) + cb.y;
    gv[g][1][1] = ax.y * b2f((u16)(zx2.y >> 16)) + ah.y * b2f((u16)(zh2.y >> 16)) + cb.y;
  }
#pragma unroll
  for (int s = 0; s < 2; ++s) {
    const int b = (bp << 1) + s;
    const size_t ob = ((size_t)b << 9) + j2;
    const float2 cp = *(const float2*)(cin + ob);
    float cn[2], hn[2];
#pragma unroll
    for (int t = 0; t < 2; ++t) {
      const float cprev = t ? cp.y : cp.x;
      const float cc = sigf(gv[0][s][t]) * cprev + sigf(gv[1][s][t]) * tanhfast(gv[3][s][t]);
      cn[t] = cc;
      hn[t] = sigf(gv[2][s][t]) * tanhfast(cc);
    }
    *(float2*)(cout + ob) = make_float2(cn[0], cn[1]);
    *(float2*)(hout + ob) = make_float2(hn[0], hn[1]);
    *(u32*)(hb + ob) = pkbf(hn[0], hn[1]);
  }
}

extern "C" void kernel_launch(void* const* d_in, const int* in_sizes, int n_in,
                              void* d_out, int out_size, void* d_ws, size_t ws_size,
                              hipStream_t stream) {
  (void)in_sizes; (void)n_in; (void)out_size; (void)ws_size;
  constexpr int B = 16384, H = 512, G = 2048, KP = 288, K1 = 512, NOUT = 256;
  constexpr int SH = 8 * 2048;  // floats per sharded stats array

  const float* x = (const float*)d_in[0];
  const float* y = (const float*)d_in[1];
  const float* h0 = (const float*)d_in[2];
  const float* c0 = (const float*)d_in[3];
  const float* Wx0 = (const float*)d_in[4];
  const float* Wh0 = (const float*)d_in[5];
  const float* gx0 = (const float*)d_in[6];
  const float* bx0 = (const float*)d_in[7];
  const float* gh0 = (const float*)d_in[8];
  const float* bh0 = (const float*)d_in[9];
  const float* Wx1 = (const float*)d_in[10];
  const float* Wh1 = (const float*)d_in[11];
  const float* gx1 = (const float*)d_in[12];
  const float* bx1 = (const float*)d_in[13];
  const float* gh1 = (const float*)d_in[14];
  const float* bh1 = (const float*)d_in[15];
  const float* Wo = (const float*)d_in[16];
  const float* bo = (const float*)d_in[17];

  char* p = (char*)d_ws;
  u16* Zx = (u16*)p;   p += (size_t)B * G * 2;
  u16* Zh = (u16*)p;   p += (size_t)B * G * 2;
  u16* h0b = (u16*)p;  p += (size_t)2 * B * H * 2;
  u16* h1b = (u16*)p;  p += (size_t)B * H * 2;   // reused for h2 bf16
  u16* inpb = (u16*)p; p += (size_t)B * KP * 2;
  u16* wx0b = (u16*)p; p += (size_t)G * KP * 2;
  u16* wh0b = (u16*)p; p += (size_t)G * K1 * 2;
  u16* wx1b = (u16*)p; p += (size_t)G * K1 * 2;
  u16* wh1b = (u16*)p; p += (size_t)G * K1 * 2;
  u16* wob = (u16*)p;  p += (size_t)NOUT * K1 * 2;
  float* stats = (float*)p; p += (size_t)8 * SH * 4;  // 8 arrays x 8 shards x 2048
  float* coef = (float*)p;  p += (size_t)6 * G * 4;

  float* out_o = (float*)d_out;                     // [B,256]
  float* h_o = out_o + (size_t)B * NOUT;            // [2,B,512]
  float* c_o = h_o + (size_t)2 * B * H;             // [2,B,512]

  hipMemsetAsync(stats, 0, (size_t)8 * SH * sizeof(float), stream);

  prep_inputs_k<<<4608 + 16384, 256, 0, stream>>>(x, y, inpb, (const float4*)h0, (u16x4*)h0b);
  prep_weights_k<<<2304 + 3072 + 128, 256, 0, stream>>>(
      Wx0, wx0b, (const float4*)Wh0, (u16x4*)wh0b, (const float4*)Wx1, (u16x4*)wx1b,
      (const float4*)Wh1, (u16x4*)wh1b, (const float4*)Wo, (u16x4*)wob);

  const dim3 blk512(512);
  const dim3 gpair(G / 256, B / 128, 2);  // (8, 128, 2) = 2048 blocks

  // layer 0
  gemm_pair<KP, K1><<<gpair, blk512, 0, stream>>>(
      inpb, wx0b, (u32*)Zx, stats + 0 * SH, stats + 1 * SH,
      h0b, wh0b, (u32*)Zh, stats + 2 * SH, stats + 3 * SH, G);
  coef_k<<<G / 256, 256, 0, stream>>>(stats, gx0, bx0, gh0, bh0, coef, 1.f / B);
  cell2_k<<<B / 2, 256, 0, stream>>>((const u32*)Zx, (const u32*)Zh, coef, c0, h_o, c_o, h1b);

  // layer 1
  gemm_pair<K1, K1><<<gpair, blk512, 0, stream>>>(
      h1b, wx1b, (u32*)Zx, stats + 4 * SH, stats + 5 * SH,
      h0b + (size_t)B * H, wh1b, (u32*)Zh, stats + 6 * SH, stats + 7 * SH, G);
  coef_k<<<G / 256, 256, 0, stream>>>(stats + 4 * SH, gx1, bx1, gh1, bh1, coef + 3 * G, 1.f / B);
  cell2_k<<<B / 2, 256, 0, stream>>>((const u32*)Zx, (const u32*)Zh, coef + 3 * G,
                                     c0 + (size_t)B * H, h_o + (size_t)B * H,
                                     c_o + (size_t)B * H, h1b);

  // output projection
  const dim3 blk(256);
  const dim3 gout(NOUT / 128, B / 128);
  gemm_out<<<gout, blk, 0, stream>>>(h1b, wob, out_o, NOUT, K1, bo);
}